// Round 11
// baseline (409.986 us; speedup 1.0000x reference)
//
#include <hip/hip_runtime.h>
#include <math.h>

typedef __attribute__((ext_vector_type(8))) short short8;
typedef __attribute__((ext_vector_type(4))) float f32x4;

#define NPED 8192
#define INVS 0.1767766952966369f   // 1/sqrt(32)

// ---- workspace layout (BYTE offsets) ----
#define B_WHH    0          // [512][128] bf16
#define B_WQKV   131072     // [640][128] bf16 (wq_s|wk|wv|wqw)
#define B_OPWE   294912     // [128][256] bf16  [opw1 | opw2@wo]
#define B_MPW1   360448     // [128][256] bf16
#define B_TDW1   425984     // [5][128][256] bf16
#define B_TDW2   753664     // [5][128][128] bf16
#define B_TDW3C  917504     // [5][32][128] bf16 prefix-summed tdw3
#define F_WIHE   958464     // [512][2] f32
#define F_BEFF   962560     // [512] f32
#define F_WV2T   964608     // [64][128] f32
#define F_BQKV   997376     // [640] f32: bq*INVS | bk_eff | bv_eff | qwbias
#define F_BEDGE  999936     // [128] f32: opb + opw2@bo
#define F_TDB3C  1000448    // [5][24] f32
#define A_FEAT   1001472    // [8192][128] bf16
#define A_QKV    3098624    // [8192][640] bf16: ctx<-Q | K0 | V0 | (unused) | QW
// end ~13.6 MB

__device__ __forceinline__ float bf2f(ushort u) {
  union { unsigned i; float f; } v; v.i = ((unsigned)u) << 16; return v.f;
}
__device__ __forceinline__ float blo(unsigned u) {
  union { unsigned i; float f; } v; v.i = u << 16; return v.f;
}
__device__ __forceinline__ float bhi(unsigned u) {
  union { unsigned i; float f; } v; v.i = u & 0xffff0000u; return v.f;
}
__device__ __forceinline__ ushort f2bf(float f) {
  union { float f; unsigned i; } v; v.f = f;
  unsigned r = v.i + 0x7fffu + ((v.i >> 16) & 1u);
  return (ushort)(r >> 16);
}

__global__ __launch_bounds__(256) void prep(
    const float* __restrict__ wih, const float* __restrict__ bih, const float* __restrict__ bhh,
    const float* __restrict__ pew, const float* __restrict__ peb,
    const float* __restrict__ wk, const float* __restrict__ wv,
    const float* __restrict__ rpw2, const float* __restrict__ rpb2,
    const float* __restrict__ bq, const float* __restrict__ bk, const float* __restrict__ bv,
    const float* __restrict__ whh, const float* __restrict__ wq, const float* __restrict__ wo,
    const float* __restrict__ opw, const float* __restrict__ opb, const float* __restrict__ bo,
    const float* __restrict__ mpw1,
    const float* __restrict__ tdw1, const float* __restrict__ tdw2,
    const float* __restrict__ tdw3, const float* __restrict__ tdb3,
    char* __restrict__ wsb) {
  int tid = blockIdx.x * 256 + threadIdx.x;
  if (tid < 512) {
    int d = tid;
    float s0 = 0.f, s1 = 0.f, sb = 0.f;
    for (int e = 0; e < 64; ++e) {
      float w = wih[d * 64 + e];
      s0 += w * pew[e * 2]; s1 += w * pew[e * 2 + 1]; sb += w * peb[e];
    }
    ((float*)(wsb + F_WIHE))[d * 2] = s0;
    ((float*)(wsb + F_WIHE))[d * 2 + 1] = s1;
    ((float*)(wsb + F_BEFF))[d] = bih[d] + bhh[d] + sb;
  } else if (tid < 49664) {           // wqkv rows 0..383
    int j = tid - 512; int n = j >> 7, k = j & 127;
    float v = (n < 128) ? wq[n * 128 + k] * INVS
                        : (n < 256) ? wk[(n - 128) * 128 + k] : wv[(n - 256) * 128 + k];
    ((ushort*)(wsb + B_WQKV))[j] = f2bf(v);
  } else if (tid < 82432) {           // opwe [128][256]: [opw1 | opw2@wo]
    int idx = tid - 49664; int o = idx >> 8, k = idx & 255;
    float s;
    if (k < 128) s = opw[o * 256 + k];
    else {
      s = 0.f;
      for (int c = 0; c < 128; ++c) s += opw[o * 256 + 128 + c] * wo[c * 128 + (k - 128)];
    }
    ((ushort*)(wsb + B_OPWE))[idx] = f2bf(s);
  } else if (tid < 115200) {          // mpw1
    int j = tid - 82432; ((ushort*)(wsb + B_MPW1))[j] = f2bf(mpw1[j]);
  } else if (tid < 279040) {          // tdw1
    int j = tid - 115200; ((ushort*)(wsb + B_TDW1))[j] = f2bf(tdw1[j]);
  } else if (tid < 360960) {          // tdw2
    int j = tid - 279040; ((ushort*)(wsb + B_TDW2))[j] = f2bf(tdw2[j]);
  } else if (tid < 381440) {          // tdw3c prefix-summed (cols 24..31 zero)
    int j = tid - 360960; int m = j >> 12, r = j & 4095, o = r >> 7, k = r & 127;
    float s = 0.f;
    if (o < 24) {
      int c = o & 1, jj = o >> 1;
      for (int jp = 0; jp <= jj; ++jp) s += tdw3[(m * 24 + jp * 2 + c) * 128 + k];
    }
    ((ushort*)(wsb + B_TDW3C))[j] = f2bf(s);
  } else if (tid < 381560) {          // tdb3c
    int j = tid - 381440; int m = j / 24, o = j % 24;
    int c = o & 1, jj = o >> 1;
    float s = 0.f;
    for (int jp = 0; jp <= jj; ++jp) s += tdb3[m * 24 + jp * 2 + c];
    ((float*)(wsb + F_TDB3C))[j] = s;
  } else if (tid < 381944) {          // bqkv[0..384)
    int d = tid - 381560;
    float s;
    if (d < 128) s = bq[d] * INVS;
    else if (d < 256) {
      int dd = d - 128; s = bk[dd];
      for (int c = 0; c < 128; ++c) s += wk[dd * 128 + c] * rpb2[c];
    } else {
      int dd = d - 256; s = bv[dd];
      for (int c = 0; c < 128; ++c) s += wv[dd * 128 + c] * rpb2[c];
    }
    ((float*)(wsb + F_BQKV))[d] = s;
  } else if (tid < 382072) {          // bedge = opb + opw2@bo
    int o = tid - 381944;
    float s = opb[o];
    for (int c = 0; c < 128; ++c) s += opw[o * 256 + 128 + c] * bo[c];
    ((float*)(wsb + F_BEDGE))[o] = s;
  } else if (tid < 390264) {          // wv2T [64][128] f32
    int idx = tid - 382072; int e = idx >> 7, hd = idx & 127;
    float s = 0.f;
    for (int c = 0; c < 128; ++c) s += wv[hd * 128 + c] * rpw2[c * 64 + e];
    ((float*)(wsb + F_WV2T))[idx] = s;
  } else if (tid < 455800) {          // whh
    int i = tid - 390264;
    ((ushort*)(wsb + B_WHH))[i] = f2bf(whh[i]);
  } else if (tid < 488568) {          // wqw rows 384..639: wk2pad@wq_s^T (direct)
    int idx = tid - 455800; int e = idx >> 7, k = idx & 127;
    int h = e >> 6, e6 = e & 63;
    float s = 0.f;
    for (int dd = 0; dd < 32; ++dd) {
      int d = h * 32 + dd;
      float wk2ed = 0.f;
      for (int c = 0; c < 128; ++c) wk2ed += wk[d * 128 + c] * rpw2[c * 64 + e6];
      s += wk2ed * wq[d * 128 + k];
    }
    ((ushort*)(wsb + B_WQKV))[(384 + e) * 128 + k] = f2bf(s * INVS);
  } else if (tid < 488824) {          // qwbias -> bqkv[384..640)
    int e = tid - 488568; int h = e >> 6, e6 = e & 63;
    float s = 0.f;
    for (int dd = 0; dd < 32; ++dd) {
      int d = h * 32 + dd;
      float wk2ed = 0.f;
      for (int c = 0; c < 128; ++c) wk2ed += wk[d * 128 + c] * rpw2[c * 64 + e6];
      s += wk2ed * bq[d];
    }
    ((float*)(wsb + F_BQKV))[384 + e] = s * INVS;
  }
}

// LSTM + fused QKV/QW projection epilogue. 32 peds/block, 512 thr = 8 waves.
__global__ __launch_bounds__(512) void lstm_qkv(
    const float* __restrict__ obs, const ushort* __restrict__ whhb,
    const float* __restrict__ wihe, const float* __restrict__ beff,
    const ushort* __restrict__ wqkv, const float* __restrict__ bqkv,
    ushort* __restrict__ feat, ushort* __restrict__ qkvb) {
  __shared__ ushort Hs[32 * 128];
  __shared__ float obs_s[8][32][2];
  int tid = threadIdx.x;
  int w = tid >> 6, l = tid & 63;
  int lm = l & 15, lg = l >> 4;
  int nb = blockIdx.x * 32;
  {
    int ts = tid >> 6, p = (tid >> 1) & 31, c = tid & 1;
    obs_s[ts][p][c] = obs[ts * (NPED * 2) + (nb + p) * 2 + c];
  }
  for (int i = tid; i < 4096; i += 512) Hs[i] = 0;
  short8 bfr[4][4];
  float wx0[4], wx1[4], be[4];
#pragma unroll
  for (int q = 0; q < 4; ++q) {
    int g = q * 128 + w * 16 + lm;
    wx0[q] = wihe[g * 2]; wx1[q] = wihe[g * 2 + 1]; be[q] = beff[g];
#pragma unroll
    for (int ks = 0; ks < 4; ++ks)
      bfr[q][ks] = *(const short8*)(const void*)&whhb[g * 128 + ks * 32 + lg * 8];
  }
  float cst[2][4] = {};
  __syncthreads();
  for (int ts = 0; ts < 8; ++ts) {
    f32x4 acc[2][4];
#pragma unroll
    for (int mi = 0; mi < 2; ++mi)
#pragma unroll
      for (int r = 0; r < 4; ++r) {
        int p = mi * 16 + lg * 4 + r;
        float ox = obs_s[ts][p][0], oy = obs_s[ts][p][1];
#pragma unroll
        for (int q = 0; q < 4; ++q)
          acc[mi][q][r] = be[q] + wx0[q] * ox + wx1[q] * oy;
      }
#pragma unroll
    for (int ks = 0; ks < 4; ++ks) {
      int p0 = lm, p1 = 16 + lm;
      short8 a0 = *(const short8*)(const void*)&Hs[p0 * 128 + ((ks * 32 + lg * 8) ^ ((p0 & 7) << 3))];
      short8 a1 = *(const short8*)(const void*)&Hs[p1 * 128 + ((ks * 32 + lg * 8) ^ ((p1 & 7) << 3))];
#pragma unroll
      for (int q = 0; q < 4; ++q) {
        acc[0][q] = __builtin_amdgcn_mfma_f32_16x16x32_bf16(a0, bfr[q][ks], acc[0][q], 0, 0, 0);
        acc[1][q] = __builtin_amdgcn_mfma_f32_16x16x32_bf16(a1, bfr[q][ks], acc[1][q], 0, 0, 0);
      }
    }
    __syncthreads();
    int d = w * 16 + lm;
#pragma unroll
    for (int mi = 0; mi < 2; ++mi)
#pragma unroll
      for (int r = 0; r < 4; ++r) {
        int p = mi * 16 + lg * 4 + r;
        float xi = acc[mi][0][r], xf = acc[mi][1][r], xg = acc[mi][2][r], xo = acc[mi][3][r];
        float ig = 1.f / (1.f + __expf(-xi));
        float fg = 1.f / (1.f + __expf(-xf));
        xg = fminf(fmaxf(xg, -30.f), 30.f);
        float eg = __expf(-2.f * xg);
        float gg = (1.f - eg) / (1.f + eg);
        float og = 1.f / (1.f + __expf(-xo));
        float cv = fg * cst[mi][r] + ig * gg;
        cst[mi][r] = cv;
        float cvc = fminf(fmaxf(cv, -30.f), 30.f);
        float ec = __expf(-2.f * cvc);
        float th = (1.f - ec) / (1.f + ec);
        ushort hb = f2bf(og * th);
        Hs[p * 128 + (d ^ ((p & 7) << 3))] = hb;
        if (ts == 7) feat[(size_t)(nb + p) * 128 + d] = hb;
      }
    __syncthreads();
  }
  // ---- fused QKV+QW: qkv[32 rows][640] = h @ wqkv^T + bqkv ----
  // 8 waves: wr2 = w>>2 (2 row groups), wc2 = w&3 (4 col groups of 160)
  int wr2 = w >> 2, wc2 = w & 3;
  f32x4 qacc[10];
#pragma unroll
  for (int i = 0; i < 10; ++i) qacc[i] = (f32x4){0.f, 0.f, 0.f, 0.f};
#pragma unroll
  for (int ks = 0; ks < 4; ++ks) {
    int p = wr2 * 16 + lm;
    short8 af = *(const short8*)(const void*)&Hs[p * 128 + ((ks * 32 + lg * 8) ^ ((p & 7) << 3))];
    int kb = ks * 32 + lg * 8;
#pragma unroll
    for (int ni = 0; ni < 10; ++ni) {
      int col = wc2 * 160 + ni * 16 + lm;
      short8 bf = *(const short8*)(const void*)&wqkv[(size_t)col * 128 + kb];
      qacc[ni] = __builtin_amdgcn_mfma_f32_16x16x32_bf16(af, bf, qacc[ni], 0, 0, 0);
    }
  }
#pragma unroll
  for (int ni = 0; ni < 10; ++ni) {
    int col = wc2 * 160 + ni * 16 + lm;
    float bv = bqkv[col];
#pragma unroll
    for (int r = 0; r < 4; ++r) {
      int row = nb + wr2 * 16 + lg * 4 + r;
      qkvb[(size_t)row * 640 + col] = f2bf(qacc[ni][r] + bv);
    }
  }
}

// Tail kernel: grid (256, 6). Per block: EDGE[32][128] into LDS, then
// y<5: TD1->TD2->traj for mode y; y==5: MP gemm + probs.
__global__ __launch_bounds__(256) void td_mp(
    const ushort* __restrict__ feat, const ushort* __restrict__ qkv,
    const ushort* __restrict__ opwe, const float* __restrict__ bedge,
    const ushort* __restrict__ w1b, const float* __restrict__ tdb1,
    const ushort* __restrict__ w2b, const float* __restrict__ tdb2,
    const ushort* __restrict__ w3c, const float* __restrict__ b3c,
    const ushort* __restrict__ mpw1b, const float* __restrict__ mpb1,
    const float* __restrict__ mpw2, const float* __restrict__ mpb2,
    const float* __restrict__ obs, float* __restrict__ out) {
  __shared__ __align__(16) char smem_raw[8576 * 2];   // 2x [32][134] bf16
  ushort* edge_s = (ushort*)smem_raw;
  ushort* slab   = (ushort*)(smem_raw + 8576);        // z<5
  float*  w2s    = (float*)(smem_raw + 8576);         // z==5: [5][128]
  float*  pc     = (float*)(smem_raw + 8576 + 2560);  // z==5: [2][16][5]
  int t = threadIdx.x, w = t >> 6, l = t & 63, lm = l & 15, lg = l >> 4;
  int wr = w >> 1, wc = w & 1;
  int z = blockIdx.y;
  int row = blockIdx.x * 32 + wr * 16 + lm;

  // ---- EDGE = [feat|ctx] @ opwe^T + bedge -> LDS (no relu) ----
  {
    f32x4 ea[4];
#pragma unroll
    for (int i = 0; i < 4; ++i) ea[i] = (f32x4){0.f, 0.f, 0.f, 0.f};
#pragma unroll
    for (int ks = 0; ks < 8; ++ks) {
      int kb = ks * 32 + lg * 8;
      const ushort* ap = (ks < 4) ? (feat + (size_t)row * 128 + kb)
                                  : (qkv + (size_t)row * 640 + (kb - 128));
      short8 af = *(const short8*)(const void*)ap;
#pragma unroll
      for (int ni = 0; ni < 4; ++ni) {
        int c = wc * 64 + ni * 16 + lm;
        short8 bf = *(const short8*)(const void*)(opwe + (size_t)c * 256 + kb);
        ea[ni] = __builtin_amdgcn_mfma_f32_16x16x32_bf16(af, bf, ea[ni], 0, 0, 0);
      }
    }
#pragma unroll
    for (int ni = 0; ni < 4; ++ni) {
      int c = wc * 64 + ni * 16 + lm;
      float bb = bedge[c];
#pragma unroll
      for (int r = 0; r < 4; ++r)
        edge_s[(wr * 16 + lg * 4 + r) * 134 + c] = f2bf(ea[ni][r] + bb);
    }
  }
  __syncthreads();

  if (z < 5) {
    int m = z;
    const ushort* W1 = w1b + (size_t)m * 32768;
    const ushort* W2 = w2b + (size_t)m * 16384;
    const ushort* W3 = w3c + (size_t)m * 4096;
    const float* B1 = tdb1 + m * 128;
    const float* B2 = tdb2 + m * 128;
    // --- TD1: [feat|EDGE] @ W1^T, K=256 ---
    f32x4 a1[4];
#pragma unroll
    for (int i = 0; i < 4; ++i) a1[i] = (f32x4){0.f, 0.f, 0.f, 0.f};
#pragma unroll
    for (int ks = 0; ks < 8; ++ks) {
      int kb = ks * 32 + lg * 8;
      short8 af;
      if (ks < 4) af = *(const short8*)(const void*)(feat + (size_t)row * 128 + kb);
      else        af = *(const short8*)(const void*)&edge_s[(wr * 16 + lm) * 134 + (kb - 128)];
#pragma unroll
      for (int ni = 0; ni < 4; ++ni) {
        short8 bf = *(const short8*)(const void*)(W1 + (size_t)(wc * 64 + ni * 16 + lm) * 256 + kb);
        a1[ni] = __builtin_amdgcn_mfma_f32_16x16x32_bf16(af, bf, a1[ni], 0, 0, 0);
      }
    }
#pragma unroll
    for (int ni = 0; ni < 4; ++ni) {
      int c = wc * 64 + ni * 16 + lm;
      float bb = B1[c];
#pragma unroll
      for (int r = 0; r < 4; ++r)
        slab[(wr * 16 + lg * 4 + r) * 134 + c] = f2bf(fmaxf(a1[ni][r] + bb, 0.f));
    }
    __syncthreads();
    // --- TD2: slab @ W2^T, K=128, in-place ---
    short8 af2[4];
#pragma unroll
    for (int ks = 0; ks < 4; ++ks)
      af2[ks] = *(const short8*)(const void*)&slab[(wr * 16 + lm) * 134 + ks * 32 + lg * 8];
    f32x4 a2[4];
#pragma unroll
    for (int i = 0; i < 4; ++i) a2[i] = (f32x4){0.f, 0.f, 0.f, 0.f};
#pragma unroll
    for (int ks = 0; ks < 4; ++ks) {
      int kb = ks * 32 + lg * 8;
#pragma unroll
      for (int ni = 0; ni < 4; ++ni) {
        short8 bf = *(const short8*)(const void*)(W2 + (size_t)(wc * 64 + ni * 16 + lm) * 128 + kb);
        a2[ni] = __builtin_amdgcn_mfma_f32_16x16x32_bf16(af2[ks], bf, a2[ni], 0, 0, 0);
      }
    }
    __syncthreads();
#pragma unroll
    for (int ni = 0; ni < 4; ++ni) {
      int c = wc * 64 + ni * 16 + lm;
      float bb = B2[c];
#pragma unroll
      for (int r = 0; r < 4; ++r)
        slab[(wr * 16 + lg * 4 + r) * 134 + c] = f2bf(fmaxf(a2[ni][r] + bb, 0.f));
    }
    __syncthreads();
    // --- traj: slab @ w3c^T (+prefix bias + last_pos) ---
    short8 af3[4], w3f[4];
#pragma unroll
    for (int ks = 0; ks < 4; ++ks) {
      af3[ks] = *(const short8*)(const void*)&slab[(wr * 16 + lm) * 134 + ks * 32 + lg * 8];
      w3f[ks] = *(const short8*)(const void*)(W3 + (size_t)(wc * 16 + lm) * 128 + ks * 32 + lg * 8);
    }
    f32x4 a3 = (f32x4){0.f, 0.f, 0.f, 0.f};
#pragma unroll
    for (int ks = 0; ks < 4; ++ks)
      a3 = __builtin_amdgcn_mfma_f32_16x16x32_bf16(af3[ks], w3f[ks], a3, 0, 0, 0);
    int o = wc * 16 + lm;
    if (o < 24) {
      float bb = b3c[m * 24 + o];
      int c = o & 1;
#pragma unroll
      for (int r = 0; r < 4; ++r) {
        int n = blockIdx.x * 32 + wr * 16 + lg * 4 + r;
        out[(size_t)n * 120 + m * 24 + o] = a3[r] + bb + obs[7 * (NPED * 2) + n * 2 + c];
      }
    }
  } else {
    // ---- MP + probs ----
    for (int i = t; i < 640; i += 256) w2s[i] = mpw2[i];
    int g = wr, ch = wc, cb = ch * 64;
    f32x4 acc[4];
#pragma unroll
    for (int i = 0; i < 4; ++i) acc[i] = (f32x4){0.f, 0.f, 0.f, 0.f};
#pragma unroll
    for (int ks = 0; ks < 8; ++ks) {
      int kb = ks * 32 + lg * 8;
      short8 af;
      if (ks < 4) af = *(const short8*)(const void*)(feat + (size_t)row * 128 + kb);
      else        af = *(const short8*)(const void*)&edge_s[(wr * 16 + lm) * 134 + (kb - 128)];
#pragma unroll
      for (int ni = 0; ni < 4; ++ni) {
        short8 bf = *(const short8*)(const void*)(mpw1b + (size_t)(cb + ni * 16 + lm) * 256 + kb);
        acc[ni] = __builtin_amdgcn_mfma_f32_16x16x32_bf16(af, bf, acc[ni], 0, 0, 0);
      }
    }
    __syncthreads();   // w2s ready (also gates edge_s reuse—none here)
    float bc[4];
#pragma unroll
    for (int ni = 0; ni < 4; ++ni) bc[ni] = mpb1[cb + ni * 16 + lm];
    float lgt[4][5];
#pragma unroll
    for (int r = 0; r < 4; ++r)
#pragma unroll
      for (int m = 0; m < 5; ++m) {
        float s = 0.f;
#pragma unroll
        for (int ni = 0; ni < 4; ++ni)
          s += fmaxf(acc[ni][r] + bc[ni], 0.f) * w2s[m * 128 + cb + ni * 16 + lm];
        lgt[r][m] = s;
      }
#pragma unroll
    for (int mask = 1; mask < 16; mask <<= 1)
#pragma unroll
      for (int r = 0; r < 4; ++r)
#pragma unroll
        for (int m = 0; m < 5; ++m)
          lgt[r][m] += __shfl_xor(lgt[r][m], mask);
    if (ch == 1 && lm < 5) {
#pragma unroll
      for (int r = 0; r < 4; ++r) pc[(g * 16 + lg * 4 + r) * 5 + lm] = lgt[r][lm];
    }
    __syncthreads();
    if (ch == 0 && lm < 5) {
#pragma unroll
      for (int r = 0; r < 4; ++r) {
        float lv[5], mx = -1e30f, sm = 0.f;
#pragma unroll
        for (int m = 0; m < 5; ++m) {
          lv[m] = lgt[r][m] + pc[(g * 16 + lg * 4 + r) * 5 + m] + mpb2[m];
          mx = fmaxf(mx, lv[m]);
        }
#pragma unroll
        for (int m = 0; m < 5; ++m) { lv[m] = expf(lv[m] - mx); sm += lv[m]; }
        int n = blockIdx.x * 32 + g * 16 + lg * 4 + r;
        out[983040 + (size_t)n * 5 + lm] = lv[lm] / sm;
      }
    }
  }
}

// attention (unchanged; row layout 640)
__global__ __launch_bounds__(256) void attn_kernel(
    const float* __restrict__ obs, ushort* QKV,
    const float* __restrict__ wv2T,
    const float* __restrict__ rpw1, const float* __restrict__ rpb1) {
  __shared__ ushort K0s[32 * 128];
  __shared__ ushort V0s[32 * 128];
  __shared__ ushort renc[4 * 32 * 64];
  __shared__ float Qi[4][128];
  __shared__ float QWs[4][256];
  __shared__ float att[4][4][32];
  __shared__ float AR[4][4][64];
  __shared__ float rpx[64], rpy[64], rpb[64];
  __shared__ float posS[32][2];
  __shared__ float posI[4][2];
  int t = threadIdx.x;
  int scene = blockIdx.x & 255, ic = blockIdx.x >> 8;
  int i0 = ic * 4, sbase = scene * 32;

  for (int idx = t; idx < 1024; idx += 256) {
    int arr = idx >> 9, j = (idx >> 4) & 31, c = idx & 15;
    short8 v = *(const short8*)(const void*)&QKV[(size_t)(sbase + j) * 640 + 128 + arr * 128 + c * 8];
    ushort* dst = arr ? V0s : K0s;
    *(short8*)(void*)&dst[j * 128 + (c ^ (j & 7)) * 8] = v;
  }
  for (int idx = t; idx < 512; idx += 256) {
    int ii = idx >> 7, d = idx & 127;
    Qi[ii][d] = bf2f(QKV[(size_t)(sbase + i0 + ii) * 640 + d]);
  }
  for (int idx = t; idx < 1024; idx += 256) {
    int ii = idx >> 8, e = idx & 255;
    QWs[ii][e] = bf2f(QKV[(size_t)(sbase + i0 + ii) * 640 + 384 + e]);
  }
  if (t < 64) posS[t >> 1][t & 1] = obs[7 * (NPED * 2) + (sbase + (t >> 1)) * 2 + (t & 1)];
  else if (t < 72) {
    int q = t - 64;
    posI[q >> 1][q & 1] = obs[7 * (NPED * 2) + (sbase + i0 + (q >> 1)) * 2 + (q & 1)];
  } else if (t >= 128 && t < 192) {
    int e = t - 128;
    rpx[e] = rpw1[e * 2]; rpy[e] = rpw1[e * 2 + 1]; rpb[e] = rpb1[e];
  }
  __syncthreads();

  for (int idx = t; idx < 1024; idx += 256) {
    int ii = idx >> 8, j = (idx >> 3) & 31, c = idx & 7;
    float dx = posS[j][0] - posI[ii][0], dy = posS[j][1] - posI[ii][1];
    short8 pk;
#pragma unroll
    for (int r = 0; r < 8; ++r) {
      int e = c * 8 + r;
      pk[r] = (short)f2bf(fmaxf(rpx[e] * dx + rpy[e] * dy + rpb[e], 0.f));
    }
    *(short8*)(void*)&renc[(ii * 32 + j) * 64 + (c ^ (j & 7)) * 8] = pk;
  }
  __syncthreads();

  for (int idx = t; idx < 512; idx += 256) {
    int ii = idx >> 7, h = (idx >> 5) & 3, j = idx & 31;
    float s = 0.f;
#pragma unroll
    for (int cc = 0; cc < 4; ++cc) {
      uint4 kv = *(const uint4*)(const void*)&K0s[j * 128 + (((h * 4 + cc) ^ (j & 7)) * 8)];
      const float4 qa = *(const float4*)&Qi[ii][h * 32 + cc * 8];
      const float4 qb = *(const float4*)&Qi[ii][h * 32 + cc * 8 + 4];
      s += blo(kv.x) * qa.x + bhi(kv.x) * qa.y + blo(kv.y) * qa.z + bhi(kv.y) * qa.w;
      s += blo(kv.z) * qb.x + bhi(kv.z) * qb.y + blo(kv.w) * qb.z + bhi(kv.w) * qb.w;
    }
#pragma unroll
    for (int c = 0; c < 8; ++c) {
      uint4 rv = *(const uint4*)(const void*)&renc[(ii * 32 + j) * 64 + ((c ^ (j & 7)) * 8)];
      const float4 ua = *(const float4*)&QWs[ii][h * 64 + c * 8];
      const float4 ub = *(const float4*)&QWs[ii][h * 64 + c * 8 + 4];
      s += blo(rv.x) * ua.x + bhi(rv.x) * ua.y + blo(rv.y) * ua.z + bhi(rv.y) * ua.w;
      s += blo(rv.z) * ub.x + bhi(rv.z) * ub.y + blo(rv.w) * ub.z + bhi(rv.w) * ub.w;
    }
    att[ii][h][j] = s;
  }
  __syncthreads();

  {
    int r = t >> 4, lj = t & 15;
    float v0 = att[r >> 2][r & 3][lj], v1 = att[r >> 2][r & 3][lj + 16];
    float mx = fmaxf(v0, v1);
    mx = fmaxf(mx, __shfl_xor(mx, 8, 16));
    mx = fmaxf(mx, __shfl_xor(mx, 4, 16));
    mx = fmaxf(mx, __shfl_xor(mx, 2, 16));
    mx = fmaxf(mx, __shfl_xor(mx, 1, 16));
    float e0 = expf(v0 - mx), e1 = expf(v1 - mx);
    float sm = e0 + e1;
    sm += __shfl_xor(sm, 8, 16);
    sm += __shfl_xor(sm, 4, 16);
    sm += __shfl_xor(sm, 2, 16);
    sm += __shfl_xor(sm, 1, 16);
    float inv = 1.f / sm;
    att[r >> 2][r & 3][lj] = e0 * inv;
    att[r >> 2][r & 3][lj + 16] = e1 * inv;
  }
  __syncthreads();

  {
    int ii = t >> 6, h = (t >> 4) & 3, e4 = t & 15;
    int c = e4 >> 1, off = (e4 & 1) * 4;
    float a0 = 0.f, a1 = 0.f, a2 = 0.f, a3 = 0.f;
    for (int j = 0; j < 32; ++j) {
      float av = att[ii][h][j];
      uint2 rv = *(const uint2*)(const void*)&renc[(ii * 32 + j) * 64 + ((c ^ (j & 7)) * 8) + off];
      a0 += av * blo(rv.x); a1 += av * bhi(rv.x);
      a2 += av * blo(rv.y); a3 += av * bhi(rv.y);
    }
    *(float4*)&AR[ii][h][e4 * 4] = make_float4(a0, a1, a2, a3);
  }
  __syncthreads();

  {
    int ii = t >> 6, l = t & 63;
    int h5 = l >> 5, hd4 = l & 31;
    int hd = hd4 * 4, h = hd >> 5;
    float c0 = 0.f, c1 = 0.f, c2 = 0.f, c3 = 0.f;
    int cch = hd >> 3, offh = hd & 7;
    for (int j = h5 * 16; j < h5 * 16 + 16; ++j) {
      float av = att[ii][h][j];
      uint2 vv = *(const uint2*)(const void*)&V0s[j * 128 + ((cch ^ (j & 7)) * 8) + offh];
      c0 += av * blo(vv.x); c1 += av * bhi(vv.x);
      c2 += av * blo(vv.y); c3 += av * bhi(vv.y);
    }
    for (int e4 = h5 * 8; e4 < h5 * 8 + 8; ++e4) {
      const float4 ar = *(const float4*)&AR[ii][h][e4 * 4];
#pragma unroll
      for (int r = 0; r < 4; ++r) {
        const float4 wv = *(const float4*)&wv2T[(e4 * 4 + r) * 128 + hd];
        float a = (r == 0) ? ar.x : (r == 1) ? ar.y : (r == 2) ? ar.z : ar.w;
        c0 += a * wv.x; c1 += a * wv.y; c2 += a * wv.z; c3 += a * wv.w;
      }
    }
    c0 += __shfl_xor(c0, 32); c1 += __shfl_xor(c1, 32);
    c2 += __shfl_xor(c2, 32); c3 += __shfl_xor(c3, 32);
    if (h5 == 0) {
      ushort4 o;
      o.x = f2bf(c0); o.y = f2bf(c1); o.z = f2bf(c2); o.w = f2bf(c3);
      *(ushort4*)(void*)&QKV[(size_t)(sbase + i0 + ii) * 640 + hd] = o;
    }
  }
}

extern "C" void kernel_launch(void* const* d_in, const int* in_sizes, int n_in,
                              void* d_out, int out_size, void* d_ws, size_t ws_size,
                              hipStream_t stream) {
  (void)in_sizes; (void)n_in; (void)out_size; (void)ws_size;
  const float* obs  = (const float*)d_in[0];
  const float* pew  = (const float*)d_in[1];
  const float* peb  = (const float*)d_in[2];
  const float* wih  = (const float*)d_in[3];
  const float* bih  = (const float*)d_in[4];
  const float* whh  = (const float*)d_in[5];
  const float* bhh  = (const float*)d_in[6];
  const float* rpw1 = (const float*)d_in[7];
  const float* rpb1 = (const float*)d_in[8];
  const float* rpw2 = (const float*)d_in[9];
  const float* rpb2 = (const float*)d_in[10];
  const float* wq   = (const float*)d_in[11];
  const float* bq   = (const float*)d_in[12];
  const float* wk   = (const float*)d_in[13];
  const float* bk   = (const float*)d_in[14];
  const float* wv   = (const float*)d_in[15];
  const float* bv   = (const float*)d_in[16];
  const float* wo   = (const float*)d_in[17];
  const float* bo   = (const float*)d_in[18];
  const float* opw  = (const float*)d_in[19];
  const float* opb  = (const float*)d_in[20];
  const float* mpw1 = (const float*)d_in[21];
  const float* mpb1 = (const float*)d_in[22];
  const float* mpw2 = (const float*)d_in[23];
  const float* mpb2 = (const float*)d_in[24];
  const float* tdw1 = (const float*)d_in[25];
  const float* tdb1 = (const float*)d_in[26];
  const float* tdw2 = (const float*)d_in[27];
  const float* tdb2 = (const float*)d_in[28];
  const float* tdw3 = (const float*)d_in[29];
  const float* tdb3 = (const float*)d_in[30];
  char* wsb = (char*)d_ws;
  float* out = (float*)d_out;

  ushort* whhb   = (ushort*)(wsb + B_WHH);
  ushort* wqkvb  = (ushort*)(wsb + B_WQKV);
  ushort* opweb  = (ushort*)(wsb + B_OPWE);
  ushort* mpw1b  = (ushort*)(wsb + B_MPW1);
  ushort* tdw1b  = (ushort*)(wsb + B_TDW1);
  ushort* tdw2b  = (ushort*)(wsb + B_TDW2);
  ushort* tdw3cb = (ushort*)(wsb + B_TDW3C);
  ushort* featb  = (ushort*)(wsb + A_FEAT);
  ushort* qkvb   = (ushort*)(wsb + A_QKV);

  prep<<<1910, 256, 0, stream>>>(wih, bih, bhh, pew, peb, wk, wv, rpw2, rpb2,
                                 bq, bk, bv, whh, wq, wo, opw, opb, bo, mpw1,
                                 tdw1, tdw2, tdw3, tdb3, wsb);
  lstm_qkv<<<256, 512, 0, stream>>>(obs, whhb, (float*)(wsb + F_WIHE),
                                    (float*)(wsb + F_BEFF), wqkvb,
                                    (float*)(wsb + F_BQKV), featb, qkvb);
  attn_kernel<<<2048, 256, 0, stream>>>(obs, qkvb, (float*)(wsb + F_WV2T), rpw1, rpb1);
  td_mp<<<dim3(256, 6), 256, 0, stream>>>(featb, qkvb, opweb, (float*)(wsb + F_BEDGE),
                                          tdw1b, tdb1, tdw2b, tdb2,
                                          tdw3cb, (float*)(wsb + F_TDB3C),
                                          mpw1b, mpb1, mpw2, mpb2, obs, out);
}

// Round 12
// 278.348 us; speedup vs baseline: 1.4729x; 1.4729x over previous
//
#include <hip/hip_runtime.h>
#include <math.h>

typedef __attribute__((ext_vector_type(8))) short short8;
typedef __attribute__((ext_vector_type(4))) float f32x4;

#define NPED 8192
#define INVS 0.1767766952966369f   // 1/sqrt(32)

// ---- workspace layout (BYTE offsets) ----
#define B_WHH    0          // [512][128] bf16
#define B_WQKV   131072     // [640][128] bf16 (wq_s|wk|wv|wqw)
#define B_WK2PAD 294912     // [256][128] bf16
#define B_OPWE   360448     // [128][256] bf16  [opw1 | opw2@wo]
#define B_MPW1   425984     // [128][256] bf16
#define B_TDW1   491520     // [5][128][256] bf16
#define B_TDW2   819200     // [5][128][128] bf16
#define B_TDW3C  983040     // [5][32][128] bf16 prefix-summed tdw3
#define F_WIHE   1024000    // [512][2] f32
#define F_BEFF   1028096    // [512] f32
#define F_WV2T   1030144    // [64][128] f32
#define F_BQKV   1062912    // [640] f32: bq*INVS | bk_eff | bv_eff | qwbias
#define F_BEDGE  1065472    // [128] f32: opb + opw2@bo
#define F_TDB3C  1065984    // [5][24] f32
#define A_FEAT   1066496    // [8192][128] bf16
#define A_QKV    3163648    // [8192][640] bf16: ctx<-Q | K0 | V0 | (unused) | QW
// end ~13.65 MB

__device__ __forceinline__ float bf2f(ushort u) {
  union { unsigned i; float f; } v; v.i = ((unsigned)u) << 16; return v.f;
}
__device__ __forceinline__ float blo(unsigned u) {
  union { unsigned i; float f; } v; v.i = u << 16; return v.f;
}
__device__ __forceinline__ float bhi(unsigned u) {
  union { unsigned i; float f; } v; v.i = u & 0xffff0000u; return v.f;
}
__device__ __forceinline__ ushort f2bf(float f) {
  union { float f; unsigned i; } v; v.f = f;
  unsigned r = v.i + 0x7fffu + ((v.i >> 16) & 1u);
  return (ushort)(r >> 16);
}

__global__ __launch_bounds__(256) void prep(
    const float* __restrict__ wih, const float* __restrict__ bih, const float* __restrict__ bhh,
    const float* __restrict__ pew, const float* __restrict__ peb,
    const float* __restrict__ wk, const float* __restrict__ wv,
    const float* __restrict__ rpw2, const float* __restrict__ rpb2,
    const float* __restrict__ bq, const float* __restrict__ bk, const float* __restrict__ bv,
    const float* __restrict__ whh, const float* __restrict__ wq, const float* __restrict__ wo,
    const float* __restrict__ opw, const float* __restrict__ opb, const float* __restrict__ bo,
    const float* __restrict__ mpw1,
    const float* __restrict__ tdw1, const float* __restrict__ tdw2,
    const float* __restrict__ tdw3, const float* __restrict__ tdb3,
    char* __restrict__ wsb) {
  int tid = blockIdx.x * 256 + threadIdx.x;
  if (tid < 512) {
    int d = tid;
    float s0 = 0.f, s1 = 0.f, sb = 0.f;
    for (int e = 0; e < 64; ++e) {
      float w = wih[d * 64 + e];
      s0 += w * pew[e * 2]; s1 += w * pew[e * 2 + 1]; sb += w * peb[e];
    }
    ((float*)(wsb + F_WIHE))[d * 2] = s0;
    ((float*)(wsb + F_WIHE))[d * 2 + 1] = s1;
    ((float*)(wsb + F_BEFF))[d] = bih[d] + bhh[d] + sb;
  } else if (tid < 49664) {           // wqkv rows 0..383
    int j = tid - 512; int n = j >> 7, k = j & 127;
    float v = (n < 128) ? wq[n * 128 + k] * INVS
                        : (n < 256) ? wk[(n - 128) * 128 + k] : wv[(n - 256) * 128 + k];
    ((ushort*)(wsb + B_WQKV))[j] = f2bf(v);
  } else if (tid < 82432) {           // wk2pad [256][128]
    int idx = tid - 49664; int r = idx >> 7, d = idx & 127;
    int h = r >> 6, e = r & 63;
    float s = 0.f;
    if ((d >> 5) == h)
      for (int c = 0; c < 128; ++c) s += wk[d * 128 + c] * rpw2[c * 64 + e];
    ((ushort*)(wsb + B_WK2PAD))[idx] = f2bf(s);
  } else if (tid < 115200) {          // opwe [128][256]: [opw1 | opw2@wo]
    int idx = tid - 82432; int o = idx >> 8, k = idx & 255;
    float s;
    if (k < 128) s = opw[o * 256 + k];
    else {
      s = 0.f;
      for (int c = 0; c < 128; ++c) s += opw[o * 256 + 128 + c] * wo[c * 128 + (k - 128)];
    }
    ((ushort*)(wsb + B_OPWE))[idx] = f2bf(s);
  } else if (tid < 147968) {          // mpw1
    int j = tid - 115200; ((ushort*)(wsb + B_MPW1))[j] = f2bf(mpw1[j]);
  } else if (tid < 311808) {          // tdw1
    int j = tid - 147968; ((ushort*)(wsb + B_TDW1))[j] = f2bf(tdw1[j]);
  } else if (tid < 393728) {          // tdw2
    int j = tid - 311808; ((ushort*)(wsb + B_TDW2))[j] = f2bf(tdw2[j]);
  } else if (tid < 414208) {          // tdw3c prefix-summed (cols 24..31 zero)
    int j = tid - 393728; int m = j >> 12, r = j & 4095, o = r >> 7, k = r & 127;
    float s = 0.f;
    if (o < 24) {
      int c = o & 1, jj = o >> 1;
      for (int jp = 0; jp <= jj; ++jp) s += tdw3[(m * 24 + jp * 2 + c) * 128 + k];
    }
    ((ushort*)(wsb + B_TDW3C))[j] = f2bf(s);
  } else if (tid < 414328) {          // tdb3c
    int j = tid - 414208; int m = j / 24, o = j % 24;
    int c = o & 1, jj = o >> 1;
    float s = 0.f;
    for (int jp = 0; jp <= jj; ++jp) s += tdb3[m * 24 + jp * 2 + c];
    ((float*)(wsb + F_TDB3C))[j] = s;
  } else if (tid < 414968) {          // bqkv [640] (tail 384+ filled by prep2)
    int d = tid - 414328;
    float s = 0.f;
    if (d < 128) s = bq[d] * INVS;
    else if (d < 256) {
      int dd = d - 128; s = bk[dd];
      for (int c = 0; c < 128; ++c) s += wk[dd * 128 + c] * rpb2[c];
    } else if (d < 384) {
      int dd = d - 256; s = bv[dd];
      for (int c = 0; c < 128; ++c) s += wv[dd * 128 + c] * rpb2[c];
    }
    ((float*)(wsb + F_BQKV))[d] = s;
  } else if (tid < 415096) {          // bedge = opb + opw2@bo
    int o = tid - 414968;
    float s = opb[o];
    for (int c = 0; c < 128; ++c) s += opw[o * 256 + 128 + c] * bo[c];
    ((float*)(wsb + F_BEDGE))[o] = s;
  } else if (tid < 423288) {          // wv2T [64][128] f32
    int idx = tid - 415096; int e = idx >> 7, hd = idx & 127;
    float s = 0.f;
    for (int c = 0; c < 128; ++c) s += wv[hd * 128 + c] * rpw2[c * 64 + e];
    ((float*)(wsb + F_WV2T))[idx] = s;
  } else if (tid < 488824) {          // whh
    int i = tid - 423288;
    ((ushort*)(wsb + B_WHH))[i] = f2bf(whh[i]);
  }
}

// prep2: wqw rows 384..639 of wqkv (= wk2pad @ wq_s^T), and qwbias.
__global__ __launch_bounds__(256) void prep2(
    const ushort* __restrict__ wk2pad, const float* __restrict__ wq,
    const float* __restrict__ bq, ushort* __restrict__ wqkv, float* __restrict__ bqkv) {
  int idx = blockIdx.x * 256 + threadIdx.x;
  if (idx < 32768) {
    int e = idx >> 7, k = idx & 127, h = e >> 6;
    float s = 0.f;
    for (int dd = 0; dd < 32; ++dd) {
      int d = h * 32 + dd;
      s += bf2f(wk2pad[e * 128 + d]) * wq[d * 128 + k];
    }
    wqkv[(384 + e) * 128 + k] = f2bf(s * INVS);
  } else if (idx < 33024) {
    int e = idx - 32768, h = e >> 6;
    float s = 0.f;
    for (int dd = 0; dd < 32; ++dd) {
      int d = h * 32 + dd;
      s += bf2f(wk2pad[e * 128 + d]) * bq[d];
    }
    bqkv[384 + e] = s * INVS;
  }
}

// LSTM + fused QKV/QW projection epilogue. 32 peds/block, 512 thr = 8 waves.
__global__ __launch_bounds__(512) void lstm_qkv(
    const float* __restrict__ obs, const ushort* __restrict__ whhb,
    const float* __restrict__ wihe, const float* __restrict__ beff,
    const ushort* __restrict__ wqkv, const float* __restrict__ bqkv,
    ushort* __restrict__ feat, ushort* __restrict__ qkvb) {
  __shared__ ushort Hs[32 * 128];
  __shared__ float obs_s[8][32][2];
  int tid = threadIdx.x;
  int w = tid >> 6, l = tid & 63;
  int lm = l & 15, lg = l >> 4;
  int nb = blockIdx.x * 32;
  {
    int ts = tid >> 6, p = (tid >> 1) & 31, c = tid & 1;
    obs_s[ts][p][c] = obs[ts * (NPED * 2) + (nb + p) * 2 + c];
  }
  for (int i = tid; i < 4096; i += 512) Hs[i] = 0;
  short8 bfr[4][4];
  float wx0[4], wx1[4], be[4];
#pragma unroll
  for (int q = 0; q < 4; ++q) {
    int g = q * 128 + w * 16 + lm;
    wx0[q] = wihe[g * 2]; wx1[q] = wihe[g * 2 + 1]; be[q] = beff[g];
#pragma unroll
    for (int ks = 0; ks < 4; ++ks)
      bfr[q][ks] = *(const short8*)(const void*)&whhb[g * 128 + ks * 32 + lg * 8];
  }
  float cst[2][4] = {};
  __syncthreads();
  for (int ts = 0; ts < 8; ++ts) {
    f32x4 acc[2][4];
#pragma unroll
    for (int mi = 0; mi < 2; ++mi)
#pragma unroll
      for (int r = 0; r < 4; ++r) {
        int p = mi * 16 + lg * 4 + r;
        float ox = obs_s[ts][p][0], oy = obs_s[ts][p][1];
#pragma unroll
        for (int q = 0; q < 4; ++q)
          acc[mi][q][r] = be[q] + wx0[q] * ox + wx1[q] * oy;
      }
#pragma unroll
    for (int ks = 0; ks < 4; ++ks) {
      int p0 = lm, p1 = 16 + lm;
      short8 a0 = *(const short8*)(const void*)&Hs[p0 * 128 + ((ks * 32 + lg * 8) ^ ((p0 & 7) << 3))];
      short8 a1 = *(const short8*)(const void*)&Hs[p1 * 128 + ((ks * 32 + lg * 8) ^ ((p1 & 7) << 3))];
#pragma unroll
      for (int q = 0; q < 4; ++q) {
        acc[0][q] = __builtin_amdgcn_mfma_f32_16x16x32_bf16(a0, bfr[q][ks], acc[0][q], 0, 0, 0);
        acc[1][q] = __builtin_amdgcn_mfma_f32_16x16x32_bf16(a1, bfr[q][ks], acc[1][q], 0, 0, 0);
      }
    }
    __syncthreads();
    int d = w * 16 + lm;
#pragma unroll
    for (int mi = 0; mi < 2; ++mi)
#pragma unroll
      for (int r = 0; r < 4; ++r) {
        int p = mi * 16 + lg * 4 + r;
        float xi = acc[mi][0][r], xf = acc[mi][1][r], xg = acc[mi][2][r], xo = acc[mi][3][r];
        float ig = 1.f / (1.f + __expf(-xi));
        float fg = 1.f / (1.f + __expf(-xf));
        xg = fminf(fmaxf(xg, -30.f), 30.f);
        float eg = __expf(-2.f * xg);
        float gg = (1.f - eg) / (1.f + eg);
        float og = 1.f / (1.f + __expf(-xo));
        float cv = fg * cst[mi][r] + ig * gg;
        cst[mi][r] = cv;
        float cvc = fminf(fmaxf(cv, -30.f), 30.f);
        float ec = __expf(-2.f * cvc);
        float th = (1.f - ec) / (1.f + ec);
        ushort hb = f2bf(og * th);
        Hs[p * 128 + (d ^ ((p & 7) << 3))] = hb;
        if (ts == 7) feat[(size_t)(nb + p) * 128 + d] = hb;
      }
    __syncthreads();
  }
  // ---- fused QKV+QW: qkv[32 rows][640] = h @ wqkv^T + bqkv ----
  int wr2 = w >> 2, wc2 = w & 3;
  f32x4 qacc[10];
#pragma unroll
  for (int i = 0; i < 10; ++i) qacc[i] = (f32x4){0.f, 0.f, 0.f, 0.f};
#pragma unroll
  for (int ks = 0; ks < 4; ++ks) {
    int p = wr2 * 16 + lm;
    short8 af = *(const short8*)(const void*)&Hs[p * 128 + ((ks * 32 + lg * 8) ^ ((p & 7) << 3))];
    int kb = ks * 32 + lg * 8;
#pragma unroll
    for (int ni = 0; ni < 10; ++ni) {
      int col = wc2 * 160 + ni * 16 + lm;
      short8 bf = *(const short8*)(const void*)&wqkv[(size_t)col * 128 + kb];
      qacc[ni] = __builtin_amdgcn_mfma_f32_16x16x32_bf16(af, bf, qacc[ni], 0, 0, 0);
    }
  }
#pragma unroll
  for (int ni = 0; ni < 10; ++ni) {
    int col = wc2 * 160 + ni * 16 + lm;
    float bv = bqkv[col];
#pragma unroll
    for (int r = 0; r < 4; ++r) {
      int row = nb + wr2 * 16 + lg * 4 + r;
      qkvb[(size_t)row * 640 + col] = f2bf(qacc[ni][r] + bv);
    }
  }
}

// Tail kernel: grid (256, 6). Per block: EDGE[32][128] into LDS, then
// y<5: TD1->TD2->traj for mode y; y==5: MP gemm + probs.
__global__ __launch_bounds__(256) void td_mp(
    const ushort* __restrict__ feat, const ushort* __restrict__ qkv,
    const ushort* __restrict__ opwe, const float* __restrict__ bedge,
    const ushort* __restrict__ w1b, const float* __restrict__ tdb1,
    const ushort* __restrict__ w2b, const float* __restrict__ tdb2,
    const ushort* __restrict__ w3c, const float* __restrict__ b3c,
    const ushort* __restrict__ mpw1b, const float* __restrict__ mpb1,
    const float* __restrict__ mpw2, const float* __restrict__ mpb2,
    const float* __restrict__ obs, float* __restrict__ out) {
  __shared__ __align__(16) char smem_raw[8576 * 2];   // 2x [32][134] bf16
  ushort* edge_s = (ushort*)smem_raw;
  ushort* slab   = (ushort*)(smem_raw + 8576);        // z<5
  float*  w2s    = (float*)(smem_raw + 8576);         // z==5: [5][128]
  float*  pc     = (float*)(smem_raw + 8576 + 2560);  // z==5: [2][16][5]
  int t = threadIdx.x, w = t >> 6, l = t & 63, lm = l & 15, lg = l >> 4;
  int wr = w >> 1, wc = w & 1;
  int z = blockIdx.y;
  int row = blockIdx.x * 32 + wr * 16 + lm;

  // ---- EDGE = [feat|ctx] @ opwe^T + bedge -> LDS (no relu) ----
  {
    f32x4 ea[4];
#pragma unroll
    for (int i = 0; i < 4; ++i) ea[i] = (f32x4){0.f, 0.f, 0.f, 0.f};
#pragma unroll
    for (int ks = 0; ks < 8; ++ks) {
      int kb = ks * 32 + lg * 8;
      const ushort* ap = (ks < 4) ? (feat + (size_t)row * 128 + kb)
                                  : (qkv + (size_t)row * 640 + (kb - 128));
      short8 af = *(const short8*)(const void*)ap;
#pragma unroll
      for (int ni = 0; ni < 4; ++ni) {
        int c = wc * 64 + ni * 16 + lm;
        short8 bf = *(const short8*)(const void*)(opwe + (size_t)c * 256 + kb);
        ea[ni] = __builtin_amdgcn_mfma_f32_16x16x32_bf16(af, bf, ea[ni], 0, 0, 0);
      }
    }
#pragma unroll
    for (int ni = 0; ni < 4; ++ni) {
      int c = wc * 64 + ni * 16 + lm;
      float bb = bedge[c];
#pragma unroll
      for (int r = 0; r < 4; ++r)
        edge_s[(wr * 16 + lg * 4 + r) * 134 + c] = f2bf(ea[ni][r] + bb);
    }
  }
  __syncthreads();

  if (z < 5) {
    int m = z;
    const ushort* W1 = w1b + (size_t)m * 32768;
    const ushort* W2 = w2b + (size_t)m * 16384;
    const ushort* W3 = w3c + (size_t)m * 4096;
    const float* B1 = tdb1 + m * 128;
    const float* B2 = tdb2 + m * 128;
    // --- TD1: [feat|EDGE] @ W1^T, K=256 ---
    f32x4 a1[4];
#pragma unroll
    for (int i = 0; i < 4; ++i) a1[i] = (f32x4){0.f, 0.f, 0.f, 0.f};
#pragma unroll
    for (int ks = 0; ks < 8; ++ks) {
      int kb = ks * 32 + lg * 8;
      short8 af;
      if (ks < 4) af = *(const short8*)(const void*)(feat + (size_t)row * 128 + kb);
      else        af = *(const short8*)(const void*)&edge_s[(wr * 16 + lm) * 134 + (kb - 128)];
#pragma unroll
      for (int ni = 0; ni < 4; ++ni) {
        short8 bf = *(const short8*)(const void*)(W1 + (size_t)(wc * 64 + ni * 16 + lm) * 256 + kb);
        a1[ni] = __builtin_amdgcn_mfma_f32_16x16x32_bf16(af, bf, a1[ni], 0, 0, 0);
      }
    }
#pragma unroll
    for (int ni = 0; ni < 4; ++ni) {
      int c = wc * 64 + ni * 16 + lm;
      float bb = B1[c];
#pragma unroll
      for (int r = 0; r < 4; ++r)
        slab[(wr * 16 + lg * 4 + r) * 134 + c] = f2bf(fmaxf(a1[ni][r] + bb, 0.f));
    }
    __syncthreads();
    // --- TD2: slab @ W2^T, K=128, in-place ---
    short8 af2[4];
#pragma unroll
    for (int ks = 0; ks < 4; ++ks)
      af2[ks] = *(const short8*)(const void*)&slab[(wr * 16 + lm) * 134 + ks * 32 + lg * 8];
    f32x4 a2[4];
#pragma unroll
    for (int i = 0; i < 4; ++i) a2[i] = (f32x4){0.f, 0.f, 0.f, 0.f};
#pragma unroll
    for (int ks = 0; ks < 4; ++ks) {
      int kb = ks * 32 + lg * 8;
#pragma unroll
      for (int ni = 0; ni < 4; ++ni) {
        short8 bf = *(const short8*)(const void*)(W2 + (size_t)(wc * 64 + ni * 16 + lm) * 128 + kb);
        a2[ni] = __builtin_amdgcn_mfma_f32_16x16x32_bf16(af2[ks], bf, a2[ni], 0, 0, 0);
      }
    }
    __syncthreads();
#pragma unroll
    for (int ni = 0; ni < 4; ++ni) {
      int c = wc * 64 + ni * 16 + lm;
      float bb = B2[c];
#pragma unroll
      for (int r = 0; r < 4; ++r)
        slab[(wr * 16 + lg * 4 + r) * 134 + c] = f2bf(fmaxf(a2[ni][r] + bb, 0.f));
    }
    __syncthreads();
    // --- traj: slab @ w3c^T (+prefix bias + last_pos) ---
    short8 af3[4], w3f[4];
#pragma unroll
    for (int ks = 0; ks < 4; ++ks) {
      af3[ks] = *(const short8*)(const void*)&slab[(wr * 16 + lm) * 134 + ks * 32 + lg * 8];
      w3f[ks] = *(const short8*)(const void*)(W3 + (size_t)(wc * 16 + lm) * 128 + ks * 32 + lg * 8);
    }
    f32x4 a3 = (f32x4){0.f, 0.f, 0.f, 0.f};
#pragma unroll
    for (int ks = 0; ks < 4; ++ks)
      a3 = __builtin_amdgcn_mfma_f32_16x16x32_bf16(af3[ks], w3f[ks], a3, 0, 0, 0);
    int o = wc * 16 + lm;
    if (o < 24) {
      float bb = b3c[m * 24 + o];
      int c = o & 1;
#pragma unroll
      for (int r = 0; r < 4; ++r) {
        int n = blockIdx.x * 32 + wr * 16 + lg * 4 + r;
        out[(size_t)n * 120 + m * 24 + o] = a3[r] + bb + obs[7 * (NPED * 2) + n * 2 + c];
      }
    }
  } else {
    // ---- MP + probs ----
    for (int i = t; i < 640; i += 256) w2s[i] = mpw2[i];
    int g = wr, ch = wc, cb = ch * 64;
    f32x4 acc[4];
#pragma unroll
    for (int i = 0; i < 4; ++i) acc[i] = (f32x4){0.f, 0.f, 0.f, 0.f};
#pragma unroll
    for (int ks = 0; ks < 8; ++ks) {
      int kb = ks * 32 + lg * 8;
      short8 af;
      if (ks < 4) af = *(const short8*)(const void*)(feat + (size_t)row * 128 + kb);
      else        af = *(const short8*)(const void*)&edge_s[(wr * 16 + lm) * 134 + (kb - 128)];
#pragma unroll
      for (int ni = 0; ni < 4; ++ni) {
        short8 bf = *(const short8*)(const void*)(mpw1b + (size_t)(cb + ni * 16 + lm) * 256 + kb);
        acc[ni] = __builtin_amdgcn_mfma_f32_16x16x32_bf16(af, bf, acc[ni], 0, 0, 0);
      }
    }
    __syncthreads();
    float bc[4];
#pragma unroll
    for (int ni = 0; ni < 4; ++ni) bc[ni] = mpb1[cb + ni * 16 + lm];
    float lgt[4][5];
#pragma unroll
    for (int r = 0; r < 4; ++r)
#pragma unroll
      for (int m = 0; m < 5; ++m) {
        float s = 0.f;
#pragma unroll
        for (int ni = 0; ni < 4; ++ni)
          s += fmaxf(acc[ni][r] + bc[ni], 0.f) * w2s[m * 128 + cb + ni * 16 + lm];
        lgt[r][m] = s;
      }
#pragma unroll
    for (int mask = 1; mask < 16; mask <<= 1)
#pragma unroll
      for (int r = 0; r < 4; ++r)
#pragma unroll
        for (int m = 0; m < 5; ++m)
          lgt[r][m] += __shfl_xor(lgt[r][m], mask);
    if (ch == 1 && lm < 5) {
#pragma unroll
      for (int r = 0; r < 4; ++r) pc[(g * 16 + lg * 4 + r) * 5 + lm] = lgt[r][lm];
    }
    __syncthreads();
    if (ch == 0 && lm < 5) {
#pragma unroll
      for (int r = 0; r < 4; ++r) {
        float lv[5], mx = -1e30f, sm = 0.f;
#pragma unroll
        for (int m = 0; m < 5; ++m) {
          lv[m] = lgt[r][m] + pc[(g * 16 + lg * 4 + r) * 5 + m] + mpb2[m];
          mx = fmaxf(mx, lv[m]);
        }
#pragma unroll
        for (int m = 0; m < 5; ++m) { lv[m] = expf(lv[m] - mx); sm += lv[m]; }
        int n = blockIdx.x * 32 + g * 16 + lg * 4 + r;
        out[983040 + (size_t)n * 5 + lm] = lv[lm] / sm;
      }
    }
  }
}

// attention (unchanged; row layout 640)
__global__ __launch_bounds__(256) void attn_kernel(
    const float* __restrict__ obs, ushort* QKV,
    const float* __restrict__ wv2T,
    const float* __restrict__ rpw1, const float* __restrict__ rpb1) {
  __shared__ ushort K0s[32 * 128];
  __shared__ ushort V0s[32 * 128];
  __shared__ ushort renc[4 * 32 * 64];
  __shared__ float Qi[4][128];
  __shared__ float QWs[4][256];
  __shared__ float att[4][4][32];
  __shared__ float AR[4][4][64];
  __shared__ float rpx[64], rpy[64], rpb[64];
  __shared__ float posS[32][2];
  __shared__ float posI[4][2];
  int t = threadIdx.x;
  int scene = blockIdx.x & 255, ic = blockIdx.x >> 8;
  int i0 = ic * 4, sbase = scene * 32;

  for (int idx = t; idx < 1024; idx += 256) {
    int arr = idx >> 9, j = (idx >> 4) & 31, c = idx & 15;
    short8 v = *(const short8*)(const void*)&QKV[(size_t)(sbase + j) * 640 + 128 + arr * 128 + c * 8];
    ushort* dst = arr ? V0s : K0s;
    *(short8*)(void*)&dst[j * 128 + (c ^ (j & 7)) * 8] = v;
  }
  for (int idx = t; idx < 512; idx += 256) {
    int ii = idx >> 7, d = idx & 127;
    Qi[ii][d] = bf2f(QKV[(size_t)(sbase + i0 + ii) * 640 + d]);
  }
  for (int idx = t; idx < 1024; idx += 256) {
    int ii = idx >> 8, e = idx & 255;
    QWs[ii][e] = bf2f(QKV[(size_t)(sbase + i0 + ii) * 640 + 384 + e]);
  }
  if (t < 64) posS[t >> 1][t & 1] = obs[7 * (NPED * 2) + (sbase + (t >> 1)) * 2 + (t & 1)];
  else if (t < 72) {
    int q = t - 64;
    posI[q >> 1][q & 1] = obs[7 * (NPED * 2) + (sbase + i0 + (q >> 1)) * 2 + (q & 1)];
  } else if (t >= 128 && t < 192) {
    int e = t - 128;
    rpx[e] = rpw1[e * 2]; rpy[e] = rpw1[e * 2 + 1]; rpb[e] = rpb1[e];
  }
  __syncthreads();

  for (int idx = t; idx < 1024; idx += 256) {
    int ii = idx >> 8, j = (idx >> 3) & 31, c = idx & 7;
    float dx = posS[j][0] - posI[ii][0], dy = posS[j][1] - posI[ii][1];
    short8 pk;
#pragma unroll
    for (int r = 0; r < 8; ++r) {
      int e = c * 8 + r;
      pk[r] = (short)f2bf(fmaxf(rpx[e] * dx + rpy[e] * dy + rpb[e], 0.f));
    }
    *(short8*)(void*)&renc[(ii * 32 + j) * 64 + (c ^ (j & 7)) * 8] = pk;
  }
  __syncthreads();

  for (int idx = t; idx < 512; idx += 256) {
    int ii = idx >> 7, h = (idx >> 5) & 3, j = idx & 31;
    float s = 0.f;
#pragma unroll
    for (int cc = 0; cc < 4; ++cc) {
      uint4 kv = *(const uint4*)(const void*)&K0s[j * 128 + (((h * 4 + cc) ^ (j & 7)) * 8)];
      const float4 qa = *(const float4*)&Qi[ii][h * 32 + cc * 8];
      const float4 qb = *(const float4*)&Qi[ii][h * 32 + cc * 8 + 4];
      s += blo(kv.x) * qa.x + bhi(kv.x) * qa.y + blo(kv.y) * qa.z + bhi(kv.y) * qa.w;
      s += blo(kv.z) * qb.x + bhi(kv.z) * qb.y + blo(kv.w) * qb.z + bhi(kv.w) * qb.w;
    }
#pragma unroll
    for (int c = 0; c < 8; ++c) {
      uint4 rv = *(const uint4*)(const void*)&renc[(ii * 32 + j) * 64 + ((c ^ (j & 7)) * 8)];
      const float4 ua = *(const float4*)&QWs[ii][h * 64 + c * 8];
      const float4 ub = *(const float4*)&QWs[ii][h * 64 + c * 8 + 4];
      s += blo(rv.x) * ua.x + bhi(rv.x) * ua.y + blo(rv.y) * ua.z + bhi(rv.y) * ua.w;
      s += blo(rv.z) * ub.x + bhi(rv.z) * ub.y + blo(rv.w) * ub.z + bhi(rv.w) * ub.w;
    }
    att[ii][h][j] = s;
  }
  __syncthreads();

  {
    int r = t >> 4, lj = t & 15;
    float v0 = att[r >> 2][r & 3][lj], v1 = att[r >> 2][r & 3][lj + 16];
    float mx = fmaxf(v0, v1);
    mx = fmaxf(mx, __shfl_xor(mx, 8, 16));
    mx = fmaxf(mx, __shfl_xor(mx, 4, 16));
    mx = fmaxf(mx, __shfl_xor(mx, 2, 16));
    mx = fmaxf(mx, __shfl_xor(mx, 1, 16));
    float e0 = expf(v0 - mx), e1 = expf(v1 - mx);
    float sm = e0 + e1;
    sm += __shfl_xor(sm, 8, 16);
    sm += __shfl_xor(sm, 4, 16);
    sm += __shfl_xor(sm, 2, 16);
    sm += __shfl_xor(sm, 1, 16);
    float inv = 1.f / sm;
    att[r >> 2][r & 3][lj] = e0 * inv;
    att[r >> 2][r & 3][lj + 16] = e1 * inv;
  }
  __syncthreads();

  {
    int ii = t >> 6, h = (t >> 4) & 3, e4 = t & 15;
    int c = e4 >> 1, off = (e4 & 1) * 4;
    float a0 = 0.f, a1 = 0.f, a2 = 0.f, a3 = 0.f;
    for (int j = 0; j < 32; ++j) {
      float av = att[ii][h][j];
      uint2 rv = *(const uint2*)(const void*)&renc[(ii * 32 + j) * 64 + ((c ^ (j & 7)) * 8) + off];
      a0 += av * blo(rv.x); a1 += av * bhi(rv.x);
      a2 += av * blo(rv.y); a3 += av * bhi(rv.y);
    }
    *(float4*)&AR[ii][h][e4 * 4] = make_float4(a0, a1, a2, a3);
  }
  __syncthreads();

  {
    int ii = t >> 6, l = t & 63;
    int h5 = l >> 5, hd4 = l & 31;
    int hd = hd4 * 4, h = hd >> 5;
    float c0 = 0.f, c1 = 0.f, c2 = 0.f, c3 = 0.f;
    int cch = hd >> 3, offh = hd & 7;
    for (int j = h5 * 16; j < h5 * 16 + 16; ++j) {
      float av = att[ii][h][j];
      uint2 vv = *(const uint2*)(const void*)&V0s[j * 128 + ((cch ^ (j & 7)) * 8) + offh];
      c0 += av * blo(vv.x); c1 += av * bhi(vv.x);
      c2 += av * blo(vv.y); c3 += av * bhi(vv.y);
    }
    for (int e4 = h5 * 8; e4 < h5 * 8 + 8; ++e4) {
      const float4 ar = *(const float4*)&AR[ii][h][e4 * 4];
#pragma unroll
      for (int r = 0; r < 4; ++r) {
        const float4 wv = *(const float4*)&wv2T[(e4 * 4 + r) * 128 + hd];
        float a = (r == 0) ? ar.x : (r == 1) ? ar.y : (r == 2) ? ar.z : ar.w;
        c0 += a * wv.x; c1 += a * wv.y; c2 += a * wv.z; c3 += a * wv.w;
      }
    }
    c0 += __shfl_xor(c0, 32); c1 += __shfl_xor(c1, 32);
    c2 += __shfl_xor(c2, 32); c3 += __shfl_xor(c3, 32);
    if (h5 == 0) {
      ushort4 o;
      o.x = f2bf(c0); o.y = f2bf(c1); o.z = f2bf(c2); o.w = f2bf(c3);
      *(ushort4*)(void*)&QKV[(size_t)(sbase + i0 + ii) * 640 + hd] = o;
    }
  }
}

extern "C" void kernel_launch(void* const* d_in, const int* in_sizes, int n_in,
                              void* d_out, int out_size, void* d_ws, size_t ws_size,
                              hipStream_t stream) {
  (void)in_sizes; (void)n_in; (void)out_size; (void)ws_size;
  const float* obs  = (const float*)d_in[0];
  const float* pew  = (const float*)d_in[1];
  const float* peb  = (const float*)d_in[2];
  const float* wih  = (const float*)d_in[3];
  const float* bih  = (const float*)d_in[4];
  const float* whh  = (const float*)d_in[5];
  const float* bhh  = (const float*)d_in[6];
  const float* rpw1 = (const float*)d_in[7];
  const float* rpb1 = (const float*)d_in[8];
  const float* rpw2 = (const float*)d_in[9];
  const float* rpb2 = (const float*)d_in[10];
  const float* wq   = (const float*)d_in[11];
  const float* bq   = (const float*)d_in[12];
  const float* wk   = (const float*)d_in[13];
  const float* bk   = (const float*)d_in[14];
  const float* wv   = (const float*)d_in[15];
  const float* bv   = (const float*)d_in[16];
  const float* wo   = (const float*)d_in[17];
  const float* bo   = (const float*)d_in[18];
  const float* opw  = (const float*)d_in[19];
  const float* opb  = (const float*)d_in[20];
  const float* mpw1 = (const float*)d_in[21];
  const float* mpb1 = (const float*)d_in[22];
  const float* mpw2 = (const float*)d_in[23];
  const float* mpb2 = (const float*)d_in[24];
  const float* tdw1 = (const float*)d_in[25];
  const float* tdb1 = (const float*)d_in[26];
  const float* tdw2 = (const float*)d_in[27];
  const float* tdb2 = (const float*)d_in[28];
  const float* tdw3 = (const float*)d_in[29];
  const float* tdb3 = (const float*)d_in[30];
  char* wsb = (char*)d_ws;
  float* out = (float*)d_out;

  ushort* whhb   = (ushort*)(wsb + B_WHH);
  ushort* wqkvb  = (ushort*)(wsb + B_WQKV);
  ushort* wk2pb  = (ushort*)(wsb + B_WK2PAD);
  ushort* opweb  = (ushort*)(wsb + B_OPWE);
  ushort* mpw1b  = (ushort*)(wsb + B_MPW1);
  ushort* tdw1b  = (ushort*)(wsb + B_TDW1);
  ushort* tdw2b  = (ushort*)(wsb + B_TDW2);
  ushort* tdw3cb = (ushort*)(wsb + B_TDW3C);
  ushort* featb  = (ushort*)(wsb + A_FEAT);
  ushort* qkvb   = (ushort*)(wsb + A_QKV);

  prep<<<1910, 256, 0, stream>>>(wih, bih, bhh, pew, peb, wk, wv, rpw2, rpb2,
                                 bq, bk, bv, whh, wq, wo, opw, opb, bo, mpw1,
                                 tdw1, tdw2, tdw3, tdb3, wsb);
  prep2<<<129, 256, 0, stream>>>(wk2pb, wq, bq, wqkvb, (float*)(wsb + F_BQKV));
  lstm_qkv<<<256, 512, 0, stream>>>(obs, whhb, (float*)(wsb + F_WIHE),
                                    (float*)(wsb + F_BEFF), wqkvb,
                                    (float*)(wsb + F_BQKV), featb, qkvb);
  attn_kernel<<<2048, 256, 0, stream>>>(obs, qkvb, (float*)(wsb + F_WV2T), rpw1, rpb1);
  td_mp<<<dim3(256, 6), 256, 0, stream>>>(featb, qkvb, opweb, (float*)(wsb + F_BEDGE),
                                          tdw1b, tdb1, tdw2b, tdb2,
                                          tdw3cb, (float*)(wsb + F_TDB3C),
                                          mpw1b, mpb1, mpw2, mpb2, obs, out);
}